// Round 7
// baseline (313.109 us; speedup 1.0000x reference)
//
#include <hip/hip_runtime.h>

#define N_NODES 50000
#define N_EDGES 800000
#define HID 128
#define OUT_STRIDE 512
#define SLICE 12500                     // src-range per slice (4 slices)
#define N2 (N_NODES * 4)                // deg2/off2 entries

#define EBLOCKS ((N_EDGES + 255) / 256)                          // 3125
#define GB0 ((N_NODES + 63) / 64)                                // 782
#define FUSE_NB ((N_NODES + 31) / 32)                            // 1563
#define SCAN2_BLOCKS ((N2 + 511) / 512)                          // 391

typedef __attribute__((ext_vector_type(8))) short short8;
typedef __attribute__((ext_vector_type(4))) float f32x4;

__device__ __forceinline__ unsigned short f2bf(float f) {
    unsigned int u = __float_as_uint(f);
    u += 0x7FFF + ((u >> 16) & 1);          // round-to-nearest-even
    return (unsigned short)(u >> 16);
}

// ---------------- pass 1: per-(node,slice) degree count + W transpose ----------------

__global__ void deg_prep_kernel(const int* __restrict__ dst, const int* __restrict__ src,
                                int* __restrict__ deg2,
                                const float* __restrict__ W0, const float* __restrict__ Ws,
                                unsigned short* __restrict__ Wt) {
    int b = blockIdx.x;
    if (b < EBLOCKS) {
        int e = b * 256 + threadIdx.x;
        if (e < N_EDGES) {
            int d = dst[e], s = src[e];
            atomicAdd(&deg2[d * 4 + s / SLICE], 1);
        }
    } else {
        // Wt[m][c][k] = W_m[k][c] bf16
        int m = b - EBLOCKS;
        const float* S = (m == 0) ? W0 : Ws + (size_t)(m - 1) * 16384;
        for (int it = 0; it < 64; ++it) {
            int idx = it * 256 + threadIdx.x;
            Wt[(size_t)m * 16384 + (idx & 127) * 128 + (idx >> 7)] = f2bf(S[idx]);
        }
    }
}

// ---------------- hierarchical exclusive scan over deg2 (N2 entries) ----------------

__global__ __launch_bounds__(512) void blocksum_kernel(
        const int* __restrict__ deg2, int* __restrict__ bsum) {
    __shared__ int ws[8];
    int i = blockIdx.x * 512 + threadIdx.x;
    int v = (i < N2) ? deg2[i] : 0;
    #pragma unroll
    for (int o = 32; o > 0; o >>= 1) v += __shfl_down(v, o, 64);
    if ((threadIdx.x & 63) == 0) ws[threadIdx.x >> 6] = v;
    __syncthreads();
    if (threadIdx.x == 0) {
        int s = 0;
        #pragma unroll
        for (int w = 0; w < 8; ++w) s += ws[w];
        bsum[blockIdx.x] = s;
    }
}

__global__ __launch_bounds__(512) void scanb_kernel(int* __restrict__ bsum) {
    __shared__ int s[512];
    int t = threadIdx.x;
    s[t] = (t < SCAN2_BLOCKS) ? bsum[t] : 0;
    __syncthreads();
    #pragma unroll
    for (int o = 1; o < 512; o <<= 1) {
        int v = (t >= o) ? s[t - o] : 0;
        __syncthreads();
        s[t] += v;
        __syncthreads();
    }
    if (t < SCAN2_BLOCKS) bsum[t] = (t == 0) ? 0 : s[t - 1];
}

__global__ __launch_bounds__(512) void scanfin_kernel(
        const int* __restrict__ deg2, const int* __restrict__ bsum,
        int* __restrict__ off2) {
    __shared__ int s[512];
    int t = threadIdx.x;
    int i = blockIdx.x * 512 + t;
    int d = (i < N2) ? deg2[i] : 0;
    s[t] = d;
    __syncthreads();
    #pragma unroll
    for (int o = 1; o < 512; o <<= 1) {
        int v = (t >= o) ? s[t - o] : 0;
        __syncthreads();
        s[t] += v;
        __syncthreads();
    }
    if (i < N2) off2[i] = bsum[blockIdx.x] + s[t] - d;
}

// ---------------- fill CSR (u16, slice-bucketed)  ∥  GEMM0 ----------------

__device__ __forceinline__ void gemm0_block(int bid, const float* __restrict__ feat,
                                            const unsigned short* __restrict__ Wt,
                                            float* __restrict__ out,
                                            unsigned short* __restrict__ hbo) {
    int wave = threadIdx.x >> 6;
    int lane = threadIdx.x & 63;
    int r0 = bid * 64 + wave * 16;
    int m15 = lane & 15;
    int kg = lane >> 4;

    int ar = r0 + m15;
    if (ar >= N_NODES) ar = N_NODES - 1;     // clamp; stores masked
    const float* arow = feat + (size_t)ar * 128 + kg * 8;
    short8 af[4];
    #pragma unroll
    for (int ks = 0; ks < 4; ++ks) {
        float4 lo = *(const float4*)(arow + ks * 32);
        float4 hi = *(const float4*)(arow + ks * 32 + 4);
        short8 s;
        s[0] = (short)f2bf(lo.x); s[1] = (short)f2bf(lo.y);
        s[2] = (short)f2bf(lo.z); s[3] = (short)f2bf(lo.w);
        s[4] = (short)f2bf(hi.x); s[5] = (short)f2bf(hi.y);
        s[6] = (short)f2bf(hi.z); s[7] = (short)f2bf(hi.w);
        af[ks] = s;
    }

    f32x4 acc[8];
    #pragma unroll
    for (int nf = 0; nf < 8; ++nf) acc[nf] = (f32x4){0.f, 0.f, 0.f, 0.f};
    #pragma unroll
    for (int nf = 0; nf < 8; ++nf) {
        const unsigned short* wrow = Wt + (size_t)(nf * 16 + m15) * 128 + kg * 8;
        #pragma unroll
        for (int ks = 0; ks < 4; ++ks) {
            short8 bf = *(const short8*)(wrow + ks * 32);
            acc[nf] = __builtin_amdgcn_mfma_f32_16x16x32_bf16(af[ks], bf, acc[nf], 0, 0, 0);
        }
    }

    #pragma unroll
    for (int j = 0; j < 4; ++j) {
        int orow = r0 + kg * 4 + j;
        if (orow < N_NODES) {
            size_t cb = (size_t)orow * OUT_STRIDE + m15;
            size_t hoff = (size_t)orow * 128 + m15;
            #pragma unroll
            for (int nf = 0; nf < 8; ++nf) {
                float v = fmaxf(acc[nf][j], 0.f);
                out[cb + nf * 16] = v;
                hbo[hoff + nf * 16] = f2bf(v);
            }
        }
    }
}

__global__ __launch_bounds__(256) void fill_gemm0_kernel(
        const int* __restrict__ src, const int* __restrict__ dst,
        const int* __restrict__ off2, int* __restrict__ cursor2,
        unsigned short* __restrict__ csr16,
        const float* __restrict__ feat, const unsigned short* __restrict__ Wt,
        float* __restrict__ out, unsigned short* __restrict__ hbo) {
    int b = blockIdx.x;
    if (b < EBLOCKS) {
        int e = b * 256 + threadIdx.x;
        if (e < N_EDGES) {
            int d = dst[e], s = src[e];
            int idx = d * 4 + s / SLICE;
            int p = atomicAdd(&cursor2[idx], 1);
            csr16[off2[idx] + p] = (unsigned short)s;
        }
    } else {
        gemm0_block(b - EBLOCKS, feat, Wt, out, hbo);
    }
}

// ---------------- fused slice-ordered aggregation + MFMA GEMM + ReLU ----------------
// Block = 512 threads (8 waves), owns 32 nodes.
// Phase 1: wave aggregates 4 nodes sequentially; per node, loop slices 0..3
//   (sub-lists bucketed by src-range; co-resident blocks hit the same ~3.2 MB
//   h-slice -> per-XCD L2 resident). Lane roles: half=lane>>5 (edge of pair),
//   q=lane&31 (dims 4q..4q+4); 2-deep unroll = 4 edge-rows in flight.
// Phase 2: wave w -> 16-row stripe (w>>2) x 32-col quarter (w&3); MFMA K=128.

__global__ __launch_bounds__(512) void agg_gemm_kernel(
        const unsigned short* __restrict__ hb, const int* __restrict__ off2,
        const int* __restrict__ deg2, const unsigned short* __restrict__ csr16,
        const unsigned short* __restrict__ Wt,
        float* __restrict__ out, unsigned short* __restrict__ hbo, int coff) {
    __shared__ unsigned short lds[32][132];
    int wave = threadIdx.x >> 6;       // 0..7
    int lane = threadIdx.x & 63;
    int half = lane >> 5;
    int q = lane & 31;
    const unsigned short* base = hb + q * 4;

    #pragma unroll
    for (int i = 0; i < 4; ++i) {
        int n = blockIdx.x * 32 + wave * 4 + i;
        float a0 = 0.f, a1 = 0.f, a2 = 0.f, a3 = 0.f;
        float b0 = 0.f, b1 = 0.f, b2 = 0.f, b3 = 0.f;
        float sc = 0.f;
        if (n < N_NODES) {
            int4 o4 = *(const int4*)(off2 + 4 * n);
            int4 d4 = *(const int4*)(deg2 + 4 * n);
            sc = 1.0f / (float)max(d4.x + d4.y + d4.z + d4.w, 1);
            #pragma unroll
            for (int pp = 0; pp < 4; ++pp) {
                int start = (pp == 0) ? o4.x : (pp == 1) ? o4.y : (pp == 2) ? o4.z : o4.w;
                int cnt   = (pp == 0) ? d4.x : (pp == 1) ? d4.y : (pp == 2) ? d4.z : d4.w;
                int e = 0;
                for (; e + 4 <= cnt; e += 4) {
                    unsigned sA = csr16[start + e + half];
                    unsigned sB = csr16[start + e + 2 + half];
                    uint2 vA = *(const uint2*)(base + sA * 128u);
                    uint2 vB = *(const uint2*)(base + sB * 128u);
                    a0 += __uint_as_float(vA.x << 16);
                    a1 += __uint_as_float(vA.x & 0xFFFF0000u);
                    a2 += __uint_as_float(vA.y << 16);
                    a3 += __uint_as_float(vA.y & 0xFFFF0000u);
                    b0 += __uint_as_float(vB.x << 16);
                    b1 += __uint_as_float(vB.x & 0xFFFF0000u);
                    b2 += __uint_as_float(vB.y << 16);
                    b3 += __uint_as_float(vB.y & 0xFFFF0000u);
                }
                if (e + 2 <= cnt) {
                    unsigned sA = csr16[start + e + half];
                    uint2 vA = *(const uint2*)(base + sA * 128u);
                    a0 += __uint_as_float(vA.x << 16);
                    a1 += __uint_as_float(vA.x & 0xFFFF0000u);
                    a2 += __uint_as_float(vA.y << 16);
                    a3 += __uint_as_float(vA.y & 0xFFFF0000u);
                    e += 2;
                }
                if (e < cnt && half == 0) {
                    unsigned sA = csr16[start + e];
                    uint2 vA = *(const uint2*)(base + sA * 128u);
                    a0 += __uint_as_float(vA.x << 16);
                    a1 += __uint_as_float(vA.x & 0xFFFF0000u);
                    a2 += __uint_as_float(vA.y << 16);
                    a3 += __uint_as_float(vA.y & 0xFFFF0000u);
                }
            }
        }
        a0 += b0; a1 += b1; a2 += b2; a3 += b3;
        a0 += __shfl_xor(a0, 32);
        a1 += __shfl_xor(a1, 32);
        a2 += __shfl_xor(a2, 32);
        a3 += __shfl_xor(a3, 32);
        if (half == 0) {
            unsigned p0 = (unsigned)f2bf(a0 * sc) | ((unsigned)f2bf(a1 * sc) << 16);
            unsigned p1 = (unsigned)f2bf(a2 * sc) | ((unsigned)f2bf(a3 * sc) << 16);
            *(uint2*)&lds[wave * 4 + i][q * 4] = make_uint2(p0, p1);
        }
    }
    __syncthreads();

    // phase 2: MFMA
    int s = wave >> 2;                 // row stripe 0..1 (16 rows)
    int colq = wave & 3;               // col quarter 0..3 (32 cols)
    int m15 = lane & 15;
    int kg = lane >> 4;
    int arow = s * 16 + m15;

    short8 af[4];
    #pragma unroll
    for (int ks = 0; ks < 4; ++ks)
        af[ks] = *(const short8*)&lds[arow][kg * 8 + ks * 32];

    f32x4 acc[2];
    acc[0] = (f32x4){0.f, 0.f, 0.f, 0.f};
    acc[1] = (f32x4){0.f, 0.f, 0.f, 0.f};
    #pragma unroll
    for (int nf = 0; nf < 2; ++nf) {
        const unsigned short* wrow = Wt + (size_t)(colq * 32 + nf * 16 + m15) * 128 + kg * 8;
        #pragma unroll
        for (int ks = 0; ks < 4; ++ks) {
            short8 bf = *(const short8*)(wrow + ks * 32);
            acc[nf] = __builtin_amdgcn_mfma_f32_16x16x32_bf16(af[ks], bf, acc[nf], 0, 0, 0);
        }
    }

    #pragma unroll
    for (int j = 0; j < 4; ++j) {
        int orow = blockIdx.x * 32 + s * 16 + kg * 4 + j;
        if (orow < N_NODES) {
            int col = colq * 32 + m15;
            size_t cb = (size_t)orow * OUT_STRIDE + coff + col;
            #pragma unroll
            for (int nf = 0; nf < 2; ++nf) {
                float v = fmaxf(acc[nf][j], 0.f);
                out[cb + nf * 16] = v;
                if (hbo) hbo[(size_t)orow * 128 + col + nf * 16] = f2bf(v);
            }
        }
    }
}

extern "C" void kernel_launch(void* const* d_in, const int* in_sizes, int n_in,
                              void* d_out, int out_size, void* d_ws, size_t ws_size,
                              hipStream_t stream) {
    const float* feat = (const float*)d_in[0];
    const int*   src  = (const int*)d_in[1];
    const int*   dst  = (const int*)d_in[2];
    const float* W0   = (const float*)d_in[3];
    const float* Ws   = (const float*)d_in[4];
    float* out = (float*)d_out;

    // workspace carve-up (~29 MB); all chunks 16B-multiples
    char* p = (char*)d_ws;
    unsigned short* hba   = (unsigned short*)p;  p += (size_t)N_NODES * HID * 2;
    unsigned short* hbb   = (unsigned short*)p;  p += (size_t)N_NODES * HID * 2;
    unsigned short* Wt    = (unsigned short*)p;  p += (size_t)4 * HID * HID * 2;
    int*   deg2    = (int*)p;                    p += (size_t)N2 * 4;
    int*   cursor2 = (int*)p;                    p += (size_t)N2 * 4;
    int*   off2    = (int*)p;                    p += (size_t)N2 * 4;
    unsigned short* csr16 = (unsigned short*)p;  p += (size_t)N_EDGES * 2;
    int*   bsum    = (int*)p;

    // deg2 and cursor2 contiguous: one memset
    hipMemsetAsync(deg2, 0, (size_t)N2 * 2 * sizeof(int), stream);

    deg_prep_kernel<<<EBLOCKS + 4, 256, 0, stream>>>(dst, src, deg2, W0, Ws, Wt);
    blocksum_kernel<<<SCAN2_BLOCKS, 512, 0, stream>>>(deg2, bsum);
    scanb_kernel<<<1, 512, 0, stream>>>(bsum);
    scanfin_kernel<<<SCAN2_BLOCKS, 512, 0, stream>>>(deg2, bsum, off2);
    fill_gemm0_kernel<<<EBLOCKS + GB0, 256, 0, stream>>>(src, dst, off2, cursor2, csr16,
                                                         feat, Wt, out, hba);

    // layer l: read h_l, write out stripe + h_{l+1} (ping-pong hba/hbb)
    agg_gemm_kernel<<<FUSE_NB, 512, 0, stream>>>(hba, off2, deg2, csr16,
                                                 Wt + 1 * HID * HID, out, hbb, 1 * HID);
    agg_gemm_kernel<<<FUSE_NB, 512, 0, stream>>>(hbb, off2, deg2, csr16,
                                                 Wt + 2 * HID * HID, out, hba, 2 * HID);
    agg_gemm_kernel<<<FUSE_NB, 512, 0, stream>>>(hba, off2, deg2, csr16,
                                                 Wt + 3 * HID * HID, out, nullptr, 3 * HID);
}